// Round 3
// baseline (444.216 us; speedup 1.0000x reference)
//
#include <hip/hip_runtime.h>
#include <cstddef>
#include <cstdint>

// Problem constants (fixed by reference file)
#define B_    256
#define V_    128000
#define T_    16
#define TOPK_ 100
#define TPB   1024
#define CAP   4096
#define NF4   (V_ / 4)    // 32000 float4 per row
#define NHIST 4096

// Fused decomposition
#define SEG    8                   // segments per row
#define CAPSEG 128                 // candidate capacity per segment (mean 64, +8 sigma)
#define SEGF4  (NF4 / SEG)         // 4000 float4 per segment
#define TPBF   256                 // fused block size
#define T0     0.996f              // speculative threshold (~512 cand/row expected)
#define NB     1024                // selection histogram bins
#define BINCAP 256                 // in-bin candidate cap

#define FULL_ITERS 15              // SEGF4 = 15*TPBF + TAIL
#define TAIL       (SEGF4 - FULL_ITERS * TPBF)   // 160

#define WS_CAND_BYTES ((size_t)B_ * SEG * CAPSEG * sizeof(float))   // 1 MiB
#define WS_CNT_BYTES  ((size_t)B_ * SEG * sizeof(int))              // 8 KiB
#define WS_DONE_BYTES ((size_t)B_ * sizeof(int))                    // 1 KiB
#define WS_NEED       (WS_CAND_BYTES + WS_CNT_BYTES + WS_DONE_BYTES)

__global__ void zero_out_kernel(float* o) {
    o[0] = 0.f; o[1] = 0.f; o[2] = 0.f;
}

// zero out[] and per-row done counters (ws is poisoned each iteration)
__global__ void init_kernel(float* out, int* done) {
    int t = threadIdx.x;
    if (t < 3) out[t] = 0.f;
    if (t < B_) done[t] = 0;
}

// ---------------------------------------------------------------------------
// Exact top-100 sum of s_vals[0..acc) via 1024-bin histogram selection.
// Bins over [lo, lo + NB/scale). Returns sum on tid==0 (undefined elsewhere).
// All candidates must lie in [lo, 1). Requires acc >= TOPK_.
// Exact in all cases: in-bin overflow falls back to serial exact top-100.
// ---------------------------------------------------------------------------
__device__ __forceinline__ float block_select_sum(
        float* s_vals, int acc, float lo, float scale,
        unsigned* s_hist, unsigned* s_chunk, float* s_bin, float* s_red,
        int* p_bstar, int* p_above, int* p_bq, int tid) {
    for (int i = tid; i < NB; i += TPBF) s_hist[i] = 0u;
    if (tid == 0) *p_bq = 0;
    __syncthreads();

    for (int i = tid; i < acc; i += TPBF) {
        int b = (int)((s_vals[i] - lo) * scale);
        b = min(max(b, 0), NB - 1);
        atomicAdd(&s_hist[b], 1u);
    }
    __syncthreads();

    {   // per-thread 4-bin chunk sums -> cheap serial suffix walk
        int base = tid << 2;
        s_chunk[tid] = s_hist[base] + s_hist[base + 1] +
                       s_hist[base + 2] + s_hist[base + 3];
    }
    __syncthreads();

    if (tid == 0) {
        int above = 0, bstar = 0;
        for (int c = (NB >> 2) - 1; c >= 0; --c) {
            int s = (int)s_chunk[c];
            if (above + s >= TOPK_) {
                for (int b = (c << 2) + 3; b >= (c << 2); --b) {
                    int cb = (int)s_hist[b];
                    if (above + cb >= TOPK_) { bstar = b; break; }
                    above += cb;
                }
                *p_bstar = bstar; *p_above = above;
                break;
            }
            above += s;
        }
    }
    __syncthreads();

    const int bstar = *p_bstar;
    float local = 0.f;
    for (int i = tid; i < acc; i += TPBF) {
        float v = s_vals[i];
        int b = (int)((v - lo) * scale);
        b = min(max(b, 0), NB - 1);
        if (b > bstar) {
            local += v;
        } else if (b == bstar) {
            int k = atomicAdd(p_bq, 1);
            if (k < BINCAP) s_bin[k] = v;
        }
    }
    s_red[tid] = local;
    __syncthreads();
    #pragma unroll
    for (int off = TPBF / 2; off > 0; off >>= 1) {
        if (tid < off) s_red[tid] += s_red[tid + off];
        __syncthreads();
    }

    float sum = 0.f;
    if (tid == 0) {
        sum = s_red[0];
        int q = *p_bq;
        int m = TOPK_ - *p_above;          // 1 <= m <= hist[bstar]
        if (q <= BINCAP) {
            for (int t = 0; t < m; ++t) {
                float bv = -1e30f; int bi = 0;
                for (int i = 0; i < q; ++i)
                    if (s_bin[i] > bv) { bv = s_bin[i]; bi = i; }
                sum += bv; s_bin[bi] = -1e30f;
            }
        } else {
            // in-bin overflow (never for uniform data): exact serial top-100
            sum = 0.f;
            for (int t = 0; t < TOPK_; ++t) {
                float bv = -1e30f; int bi = 0;
                for (int i = 0; i < acc; ++i)
                    if (s_vals[i] > bv) { bv = s_vals[i]; bi = i; }
                sum += bv; s_vals[bi] = -1e30f;
            }
        }
    }
    return sum;
}

// ---------------------------------------------------------------------------
// Fused kernel: 8 blocks per row stream their 64 KB segment at full
// occupancy; the LAST block to finish a row (device-scope atomic + fences)
// gathers the row's candidates and does histogram selection inline.
// ---------------------------------------------------------------------------
__global__ __launch_bounds__(TPBF) void fused_kernel(
        const float* __restrict__ sparse,
        const int*   __restrict__ tids,
        float*       __restrict__ cand,   // [B][SEG][CAPSEG]
        int*         __restrict__ cnt,    // [B][SEG]
        int*         __restrict__ done,   // [B]
        float*       __restrict__ out) {
    __shared__ float    s_vals[SEG * CAPSEG];   // 1024: collect (first 128) / gather
    __shared__ unsigned s_hist[NB];
    __shared__ unsigned s_chunk[NB / 4];
    __shared__ float    s_bin[BINCAP];
    __shared__ float    s_red[TPBF];
    __shared__ int      s_ids[T_];
    __shared__ int      s_scnt[SEG];
    __shared__ int      s_soff[SEG + 1];
    __shared__ int      s_cnt, s_last, s_flag, s_bstar, s_above, s_bq, s_c2;

    const int gb  = blockIdx.x;
    const int row = gb >> 3;
    const int seg = gb & 7;
    const int tid = threadIdx.x;

    if (tid < T_) s_ids[tid] = tids[row * T_ + tid];
    if (tid == 0) s_cnt = 0;
    __syncthreads();

    const float* __restrict__ rp = sparse + (size_t)row * V_;

    // ---- target + margin losses: one block per row (seg 0), lanes 0..15 ----
    if (seg == 0 && tid < T_) {
        float x  = rp[s_ids[tid]];
        float tl = -logf(x + 1e-8f);
        float ml = fmaxf(1.0f - x, 0.0f);
        #pragma unroll
        for (int off = 8; off > 0; off >>= 1) {
            tl += __shfl_down(tl, off);
            ml += __shfl_down(ml, off);
        }
        if (tid == 0) {
            atomicAdd(out + 0, tl * (1.0f / (B_ * T_)));
            atomicAdd(out + 1, ml * (1.0f / (B_ * T_)));
        }
    }

    // ---- streaming collect over this segment (static trips, 5-deep ILP) ----
    const float4* __restrict__ rp4 = (const float4*)rp + seg * SEGF4;
    const int colbase = (seg * SEGF4) << 2;

    #pragma unroll 5
    for (int it = 0; it < FULL_ITERS; ++it) {
        const int idx = it * TPBF + tid;
        float4 v = rp4[idx];
        float mx = fmaxf(fmaxf(v.x, v.y), fmaxf(v.z, v.w));
        if (mx >= T0) {                        // taken ~1.6% of iterations
            int col = colbase + (idx << 2);
            float xs[4] = {v.x, v.y, v.z, v.w};
            #pragma unroll
            for (int c = 0; c < 4; ++c) {
                float x = xs[c];
                if (x >= T0) {
                    int cc = col + c;
                    bool is_t = false;
                    #pragma unroll
                    for (int j = 0; j < T_; ++j) is_t |= (cc == s_ids[j]);
                    if (!is_t) {
                        int k = atomicAdd(&s_cnt, 1);
                        if (k < CAPSEG) s_vals[k] = x;
                    }
                }
            }
        }
    }
    if (tid < TAIL) {
        const int idx = FULL_ITERS * TPBF + tid;
        float4 v = rp4[idx];
        float mx = fmaxf(fmaxf(v.x, v.y), fmaxf(v.z, v.w));
        if (mx >= T0) {
            int col = colbase + (idx << 2);
            float xs[4] = {v.x, v.y, v.z, v.w};
            #pragma unroll
            for (int c = 0; c < 4; ++c) {
                float x = xs[c];
                if (x >= T0) {
                    int cc = col + c;
                    bool is_t = false;
                    #pragma unroll
                    for (int j = 0; j < T_; ++j) is_t |= (cc == s_ids[j]);
                    if (!is_t) {
                        int k = atomicAdd(&s_cnt, 1);
                        if (k < CAPSEG) s_vals[k] = x;
                    }
                }
            }
        }
    }
    __syncthreads();

    {   // publish this segment's candidates + raw count
        int lc = s_cnt;
        int w  = min(lc, CAPSEG);
        float* __restrict__ dst = cand + (size_t)gb * CAPSEG;
        for (int i = tid; i < w; i += TPBF) dst[i] = s_vals[i];
        if (tid == 0) cnt[gb] = lc;            // raw -> overflow detectable
    }

    // ---- last-block-per-row election (device-scope) ----
    __threadfence();
    if (tid == 0) s_last = (atomicAdd(&done[row], 1) == SEG - 1);
    __syncthreads();
    if (!s_last) return;
    __threadfence();                            // acquire other blocks' writes

    // ---- gather per-segment counts, prefix, validate ----
    if (tid < SEG) s_scnt[tid] = cnt[row * SEG + tid];
    __syncthreads();
    if (tid == 0) {
        int acc = 0, bad = 0;
        #pragma unroll
        for (int s = 0; s < SEG; ++s) {
            int c = s_scnt[s];
            bad |= (c > CAPSEG);
            int cc = min(c, CAPSEG);
            s_scnt[s] = cc;
            s_soff[s] = acc;
            acc += cc;
        }
        s_soff[SEG] = acc;                      // <= 1024
        s_flag = bad || (acc < TOPK_);
    }
    __syncthreads();

    if (!s_flag) {
        // ---- gather all candidates into LDS (8 segments x 32 lanes) ----
        const int sg = tid >> 5, ln = tid & 31;
        const float* __restrict__ src =
            cand + (size_t)(row * SEG + sg) * CAPSEG;
        const int off = s_soff[sg], len = s_scnt[sg];
        for (int i = ln; i < len; i += 32) s_vals[off + i] = src[i];
        __syncthreads();

        float sum = block_select_sum(s_vals, s_soff[SEG],
                                     T0, (float)NB / (1.0f - T0),
                                     s_hist, s_chunk, s_bin, s_red,
                                     &s_bstar, &s_above, &s_bq, tid);
        if (tid == 0) atomicAdd(out + 2, sum * (1.0f / (B_ * TOPK_)));
    } else {
        // ---- exact fallback: full-row 1024-bin histogram rescan ----
        for (int i = tid; i < NB; i += TPBF) s_hist[i] = 0u;
        __syncthreads();
        const float4* __restrict__ rr4 = (const float4*)rp;
        for (int i = tid; i < NF4; i += TPBF) {
            float4 v = rr4[i];
            float xs[4] = {v.x, v.y, v.z, v.w};
            #pragma unroll
            for (int c = 0; c < 4; ++c) {
                int b = (int)(xs[c] * (float)NB);
                b = min(max(b, 0), NB - 1);
                atomicAdd(&s_hist[b], 1u);
            }
        }
        __syncthreads();
        if (tid == 0) {
            for (int j = 0; j < T_; ++j) {      // remove unique target columns
                int id = s_ids[j];
                bool dup = false;
                for (int q = 0; q < j; ++q) dup = dup || (s_ids[q] == id);
                if (!dup) {
                    int b = (int)(rp[id] * (float)NB);
                    b = min(max(b, 0), NB - 1);
                    s_hist[b]--;
                }
            }
            int above = 0, b = NB - 1;
            for (; b >= 0; --b) {
                int cb = (int)s_hist[b];
                if (above + cb >= TOPK_) break;
                above += cb;
            }
            s_bstar = max(b, 0);
            s_c2 = 0;
        }
        __syncthreads();
        const int b1 = s_bstar;
        const float lo = (float)b1 / (float)NB;
        for (int i = tid; i < NF4; i += TPBF) {
            float4 v = rr4[i];
            int col = i << 2;
            float xs[4] = {v.x, v.y, v.z, v.w};
            #pragma unroll
            for (int c = 0; c < 4; ++c) {
                float x = xs[c];
                int b = (int)(x * (float)NB);
                b = min(max(b, 0), NB - 1);
                if (b >= b1) {
                    int cc = col + c;
                    bool is_t = false;
                    #pragma unroll
                    for (int j = 0; j < T_; ++j) is_t |= (cc == s_ids[j]);
                    if (!is_t) {
                        int k = atomicAdd(&s_c2, 1);
                        if (k < SEG * CAPSEG) s_vals[k] = x;
                    }
                }
            }
        }
        __syncthreads();
        int c2 = min(s_c2, SEG * CAPSEG);
        float sum = block_select_sum(s_vals, c2,
                                     lo, (float)NB / (1.0f - lo),
                                     s_hist, s_chunk, s_bin, s_red,
                                     &s_bstar, &s_above, &s_bq, tid);
        if (tid == 0) atomicAdd(out + 2, sum * (1.0f / (B_ * TOPK_)));
    }
}

// ---------------------------------------------------------------------------
// Proven single-kernel path, used only if the workspace is too small.
// ---------------------------------------------------------------------------
__global__ __launch_bounds__(TPB) void row_kernel(
        const float* __restrict__ sparse,
        const int*   __restrict__ tids,
        float*       __restrict__ out) {
    __shared__ float    s_cand[CAP];
    __shared__ unsigned s_hist[NHIST];
    __shared__ int      s_ids[T_];
    __shared__ int      s_cnt;
    __shared__ int      s_bstar;
    __shared__ float    s_red[128];

    const int row = blockIdx.x;
    const int tid = threadIdx.x;
    const float* __restrict__ rp = sparse + (size_t)row * V_;

    if (tid < T_) s_ids[tid] = tids[row * T_ + tid];
    if (tid == 0) s_cnt = 0;
    __syncthreads();

    if (tid < T_) {
        float x  = rp[s_ids[tid]];
        float tl = -logf(x + 1e-8f);
        float ml = fmaxf(1.0f - x, 0.0f);
        #pragma unroll
        for (int off = 8; off > 0; off >>= 1) {
            tl += __shfl_down(tl, off);
            ml += __shfl_down(ml, off);
        }
        if (tid == 0) {
            atomicAdd(out + 0, tl * (1.0f / (B_ * T_)));
            atomicAdd(out + 1, ml * (1.0f / (B_ * T_)));
        }
    }

    const float4* rp4 = (const float4*)rp;
    for (int i = tid; i < NF4; i += TPB) {
        float4 v = rp4[i];
        int col = i << 2;
        float xs[4] = {v.x, v.y, v.z, v.w};
        #pragma unroll
        for (int c = 0; c < 4; ++c) {
            float x = xs[c];
            if (x >= T0) {
                int cc = col + c;
                bool is_t = false;
                #pragma unroll
                for (int j = 0; j < T_; ++j) is_t |= (cc == s_ids[j]);
                if (!is_t) {
                    int k = atomicAdd(&s_cnt, 1);
                    if (k < CAP) s_cand[k] = x;
                }
            }
        }
    }
    __syncthreads();

    int cnt = s_cnt;
    if (cnt < TOPK_ || cnt > CAP) {
        for (int i = tid; i < NHIST; i += TPB) s_hist[i] = 0u;
        __syncthreads();
        for (int i = tid; i < NF4; i += TPB) {
            float4 v = rp4[i];
            float xs[4] = {v.x, v.y, v.z, v.w};
            #pragma unroll
            for (int c = 0; c < 4; ++c) {
                int b = (int)(xs[c] * (float)NHIST);
                b = min(max(b, 0), NHIST - 1);
                atomicAdd(&s_hist[b], 1u);
            }
        }
        __syncthreads();
        if (tid == 0) {
            for (int j = 0; j < T_; ++j) {
                int id = s_ids[j];
                bool dup = false;
                for (int q = 0; q < j; ++q) dup = dup || (s_ids[q] == id);
                if (!dup) {
                    int b = (int)(rp[id] * (float)NHIST);
                    b = min(max(b, 0), NHIST - 1);
                    s_hist[b]--;
                }
            }
            int acc = 0, b = NHIST - 1;
            for (; b >= 0; --b) {
                acc += (int)s_hist[b];
                if (acc >= TOPK_) break;
            }
            s_bstar = max(b, 0);
            s_cnt = 0;
        }
        __syncthreads();
        int bstar = s_bstar;
        for (int i = tid; i < NF4; i += TPB) {
            float4 v = rp4[i];
            int col = i << 2;
            float xs[4] = {v.x, v.y, v.z, v.w};
            #pragma unroll
            for (int c = 0; c < 4; ++c) {
                float x = xs[c];
                int b = (int)(x * (float)NHIST);
                b = min(max(b, 0), NHIST - 1);
                if (b >= bstar) {
                    int cc = col + c;
                    bool is_t = false;
                    #pragma unroll
                    for (int j = 0; j < T_; ++j) is_t |= (cc == s_ids[j]);
                    if (!is_t) {
                        int k = atomicAdd(&s_cnt, 1);
                        if (k < CAP) s_cand[k] = x;
                    }
                }
            }
        }
        __syncthreads();
        cnt = min(s_cnt, CAP);
    }

    int n2 = 128;
    while (n2 < cnt) n2 <<= 1;
    for (int i = cnt + tid; i < n2; i += TPB) s_cand[i] = -1e30f;
    __syncthreads();

    for (int k = 2; k <= n2; k <<= 1) {
        for (int j = k >> 1; j > 0; j >>= 1) {
            for (int i = tid; i < n2; i += TPB) {
                int p = i ^ j;
                if (p > i) {
                    float a = s_cand[i], b = s_cand[p];
                    bool asc = ((i & k) == 0);
                    if (asc ? (a > b) : (a < b)) {
                        s_cand[i] = b; s_cand[p] = a;
                    }
                }
            }
            __syncthreads();
        }
    }

    if (tid < 128) {
        float v = (tid < TOPK_) ? s_cand[n2 - 1 - tid] : 0.f;
        s_red[tid] = v;
    }
    __syncthreads();
    #pragma unroll
    for (int off = 64; off > 0; off >>= 1) {
        if (tid < off) s_red[tid] += s_red[tid + off];
        __syncthreads();
    }
    if (tid == 0) atomicAdd(out + 2, s_red[0] * (1.0f / (B_ * TOPK_)));
}

extern "C" void kernel_launch(void* const* d_in, const int* in_sizes, int n_in,
                              void* d_out, int out_size, void* d_ws, size_t ws_size,
                              hipStream_t stream) {
    const float* sparse = (const float*)d_in[0];
    const int*   tids   = (const int*)d_in[1];
    float*       out    = (float*)d_out;

    if (d_ws != nullptr && ws_size >= WS_NEED) {
        float* cand = (float*)d_ws;
        int*   cnt  = (int*)((char*)d_ws + WS_CAND_BYTES);
        int*   done = (int*)((char*)d_ws + WS_CAND_BYTES + WS_CNT_BYTES);
        init_kernel<<<1, 256, 0, stream>>>(out, done);
        fused_kernel<<<B_ * SEG, TPBF, 0, stream>>>(sparse, tids, cand, cnt, done, out);
    } else {
        zero_out_kernel<<<1, 1, 0, stream>>>(out);
        row_kernel<<<B_, TPB, 0, stream>>>(sparse, tids, out);
    }
}

// Round 4
// 195.473 us; speedup vs baseline: 2.2725x; 2.2725x over previous
//
#include <hip/hip_runtime.h>
#include <cstddef>
#include <cstdint>

// Problem constants (fixed by reference file)
#define B_    256
#define V_    128000
#define T_    16
#define TOPK_ 100
#define TPB   1024
#define CAP   4096
#define NF4   (V_ / 4)      // 32000 float4 per row
#define NHIST 4096          // fallback histogram bins over [0,1)
#define NB    1024          // selection histogram bins over [lo,1)
#define BINCAP 256          // in-bin candidate cap for exact tie handling
#define T0    0.996f        // speculative threshold (~512 candidates/row expected)

__global__ void zero_out_kernel(float* o) {
    o[0] = 0.f; o[1] = 0.f; o[2] = 0.f;
}

// ---------------------------------------------------------------------------
// One block per row (256 blocks x 1024 threads, 1 block/CU, 16 waves).
// 1) Stream the row with explicit 4-deep float4 load batches (ILP -> BW).
// 2) Collect values >= T0 (excluding target cols) into LDS.
// 3) Exact top-100 sum via 1024-bin histogram selection (~6 barriers),
//    with exact in-bin tie handling. Proven full-row NHIST fallback if the
//    speculative threshold under/overflows. No workspace, no fences.
// ---------------------------------------------------------------------------
__global__ __launch_bounds__(TPB) void row_kernel(
        const float* __restrict__ sparse,
        const int*   __restrict__ tids,
        float*       __restrict__ out) {
    __shared__ float    s_cand[CAP];        // 16 KB
    __shared__ unsigned s_hist[NHIST];      // 16 KB (fallback uses all, select uses first NB)
    __shared__ unsigned s_chunk[NB / 4];    // 1 KB
    __shared__ float    s_bin[BINCAP];      // 1 KB
    __shared__ float    s_wred[16];
    __shared__ int      s_ids[T_];
    __shared__ int      s_cnt, s_bq, s_bstar, s_above;

    const int row = blockIdx.x;
    const int tid = threadIdx.x;
    const float* __restrict__ rp = sparse + (size_t)row * V_;

    if (tid < T_) s_ids[tid] = tids[row * T_ + tid];
    if (tid == 0) { s_cnt = 0; s_bq = 0; }
    __syncthreads();

    // ---- target loss + margin loss (lanes 0..15 of wave 0) ----
    if (tid < T_) {
        float x  = rp[s_ids[tid]];
        float tl = -logf(x + 1e-8f);
        float ml = fmaxf(1.0f - x, 0.0f);
        #pragma unroll
        for (int off = 8; off > 0; off >>= 1) {
            tl += __shfl_down(tl, off);
            ml += __shfl_down(ml, off);
        }
        if (tid == 0) {
            atomicAdd(out + 0, tl * (1.0f / (B_ * T_)));
            atomicAdd(out + 1, ml * (1.0f / (B_ * T_)));
        }
    }

    // ---- streaming collect: 4-deep explicit load batches ----
    const float4* __restrict__ rp4 = (const float4*)rp;

    auto proc = [&](float4 v, int i4) {
        float mx = fmaxf(fmaxf(v.x, v.y), fmaxf(v.z, v.w));
        if (mx >= T0) {                       // taken ~1.6% of the time
            int col = i4 << 2;
            float xs[4] = {v.x, v.y, v.z, v.w};
            #pragma unroll
            for (int c = 0; c < 4; ++c) {
                float x = xs[c];
                if (x >= T0) {
                    int cc = col + c;
                    bool is_t = false;
                    #pragma unroll
                    for (int j = 0; j < T_; ++j) is_t |= (cc == s_ids[j]);
                    if (!is_t) {
                        int k = atomicAdd(&s_cnt, 1);
                        if (k < CAP) s_cand[k] = x;
                    }
                }
            }
        }
    };

    // NF4 = 32000 = 7*(4*1024) + 3*1024 + 256
    #pragma unroll
    for (int g = 0; g < 7; ++g) {
        const int base = g * 4 * TPB + tid;
        float4 va = rp4[base];
        float4 vb = rp4[base + TPB];
        float4 vc = rp4[base + 2 * TPB];
        float4 vd = rp4[base + 3 * TPB];
        proc(va, base);
        proc(vb, base + TPB);
        proc(vc, base + 2 * TPB);
        proc(vd, base + 3 * TPB);
    }
    {
        const int base = 28 * TPB + tid;
        float4 va = rp4[base];
        float4 vb = rp4[base + TPB];
        float4 vc = rp4[base + 2 * TPB];
        proc(va, base);
        proc(vb, base + TPB);
        proc(vc, base + 2 * TPB);
    }
    if (tid < 256) {
        const int idx = 31 * TPB + tid;       // 31744 + tid -> 32000
        float4 v = rp4[idx];
        proc(v, idx);
    }
    __syncthreads();

    int cnt = s_cnt;
    float lo = T0;

    // ---- exact fallback: full-row NHIST histogram re-threshold (proven) ----
    if (cnt < TOPK_ || cnt > CAP) {
        for (int i = tid; i < NHIST; i += TPB) s_hist[i] = 0u;
        __syncthreads();
        for (int i = tid; i < NF4; i += TPB) {
            float4 v = rp4[i];
            float xs[4] = {v.x, v.y, v.z, v.w};
            #pragma unroll
            for (int c = 0; c < 4; ++c) {
                int b = (int)(xs[c] * (float)NHIST);
                b = min(max(b, 0), NHIST - 1);
                atomicAdd(&s_hist[b], 1u);
            }
        }
        __syncthreads();
        if (tid == 0) {
            for (int j = 0; j < T_; ++j) {    // remove unique target columns
                int id = s_ids[j];
                bool dup = false;
                for (int q = 0; q < j; ++q) dup = dup || (s_ids[q] == id);
                if (!dup) {
                    int b = (int)(rp[id] * (float)NHIST);
                    b = min(max(b, 0), NHIST - 1);
                    s_hist[b]--;
                }
            }
            int acc = 0, b = NHIST - 1;
            for (; b >= 0; --b) {
                acc += (int)s_hist[b];
                if (acc >= TOPK_) break;
            }
            s_bstar = max(b, 0);
            s_cnt = 0;
        }
        __syncthreads();
        const int bstar = s_bstar;
        lo = (float)bstar / (float)NHIST;
        for (int i = tid; i < NF4; i += TPB) {
            float4 v = rp4[i];
            int col = i << 2;
            float xs[4] = {v.x, v.y, v.z, v.w};
            #pragma unroll
            for (int c = 0; c < 4; ++c) {
                float x = xs[c];
                int b = (int)(x * (float)NHIST);
                b = min(max(b, 0), NHIST - 1);
                if (b >= bstar) {
                    int cc = col + c;
                    bool is_t = false;
                    #pragma unroll
                    for (int j = 0; j < T_; ++j) is_t |= (cc == s_ids[j]);
                    if (!is_t) {
                        int k = atomicAdd(&s_cnt, 1);
                        if (k < CAP) s_cand[k] = x;
                    }
                }
            }
        }
        __syncthreads();
        cnt = min(s_cnt, CAP);
    }

    // ---- exact top-100 sum via NB-bin histogram selection over [lo, 1) ----
    const float scale = (float)NB / (1.0f - lo);

    for (int i = tid; i < NB; i += TPB) s_hist[i] = 0u;
    __syncthreads();

    for (int i = tid; i < cnt; i += TPB) {
        int b = (int)((s_cand[i] - lo) * scale);
        b = min(max(b, 0), NB - 1);
        atomicAdd(&s_hist[b], 1u);
    }
    __syncthreads();

    if (tid < NB / 4) {                        // 4-bin chunk sums
        int base = tid << 2;
        s_chunk[tid] = s_hist[base] + s_hist[base + 1] +
                       s_hist[base + 2] + s_hist[base + 3];
    }
    __syncthreads();

    if (tid == 0) {                            // serial suffix walk (expected ~50 chunks)
        int above = 0, bstar = 0;
        for (int c = (NB >> 2) - 1; c >= 0; --c) {
            int s = (int)s_chunk[c];
            if (above + s >= TOPK_) {
                for (int b = (c << 2) + 3; b >= (c << 2); --b) {
                    int cb = (int)s_hist[b];
                    if (above + cb >= TOPK_) { bstar = b; break; }
                    above += cb;
                }
                s_bstar = bstar;
                s_above = above;
                break;
            }
            above += s;
        }
    }
    __syncthreads();

    const int b2 = s_bstar;
    float local = 0.f;
    for (int i = tid; i < cnt; i += TPB) {
        float v = s_cand[i];
        int b = (int)((v - lo) * scale);
        b = min(max(b, 0), NB - 1);
        if (b > b2) {
            local += v;
        } else if (b == b2) {
            int k = atomicAdd(&s_bq, 1);
            if (k < BINCAP) s_bin[k] = v;
        }
    }
    #pragma unroll
    for (int off = 32; off > 0; off >>= 1) local += __shfl_down(local, off);
    if ((tid & 63) == 0) s_wred[tid >> 6] = local;
    __syncthreads();

    if (tid == 0) {
        float sum = 0.f;
        #pragma unroll
        for (int w = 0; w < 16; ++w) sum += s_wred[w];
        int q = s_bq;
        int m = TOPK_ - s_above;               // 1 <= m <= hist[b2] <= q (if q<=BINCAP)
        if (q <= BINCAP) {
            for (int t = 0; t < m; ++t) {
                float bv = -1e30f; int bi = 0;
                for (int i = 0; i < q; ++i)
                    if (s_bin[i] > bv) { bv = s_bin[i]; bi = i; }
                sum += bv; s_bin[bi] = -1e30f;
            }
        } else {
            // in-bin overflow (never for this data): exact serial top-100
            sum = 0.f;
            for (int t = 0; t < TOPK_; ++t) {
                float bv = -1e30f; int bi = 0;
                for (int i = 0; i < cnt; ++i)
                    if (s_cand[i] > bv) { bv = s_cand[i]; bi = i; }
                sum += bv; s_cand[bi] = -1e30f;
            }
        }
        atomicAdd(out + 2, sum * (1.0f / (B_ * TOPK_)));
    }
}

extern "C" void kernel_launch(void* const* d_in, const int* in_sizes, int n_in,
                              void* d_out, int out_size, void* d_ws, size_t ws_size,
                              hipStream_t stream) {
    const float* sparse = (const float*)d_in[0];
    const int*   tids   = (const int*)d_in[1];
    float*       out    = (float*)d_out;

    zero_out_kernel<<<1, 1, 0, stream>>>(out);
    row_kernel<<<B_, TPB, 0, stream>>>(sparse, tids, out);
}